// Round 10
// baseline (198.920 us; speedup 1.0000x reference)
//
#include <hip/hip_runtime.h>
#include <hip/hip_bf16.h>
#include <math.h>

#define BB 4
#define TT 12
#define NN 2000
#define KK 8
#define CC 32
#define EPSF 1e-5f
#define LISTCAP 16
#define NSITES (BB * TT * NN)   // 96000

typedef unsigned short u16;
typedef __bf16 bf16x8 __attribute__((ext_vector_type(8)));
typedef float  f32x4  __attribute__((ext_vector_type(4)));

__device__ __forceinline__ u16 f2bf(float x) {
    union { __hip_bfloat16 h; u16 u; } c;
    c.h = __float2bfloat16(x);   // RNE
    return c.u;
}
__device__ __forceinline__ float bf2f(u16 u) {
    return __uint_as_float(((unsigned)u) << 16);
}
__device__ __forceinline__ float mask6(float v) {
    if (isnan(v)) v = 6.0f;
    if (isinf(v)) v = 0.0f;
    return fminf(v, 6.0f);
}
__device__ __forceinline__ unsigned long long shflx64(unsigned long long v, int m) {
    int lo = __shfl_xor((int)(unsigned)(v & 0xffffffffull), m, 64);
    int hi = __shfl_xor((int)(unsigned)(v >> 32), m, 64);
    return ((unsigned long long)(unsigned)hi << 32) | (unsigned)lo;
}

// ---------------------------------------------------------------------------
// Kernel A: wave-per-row top-K. R10 rewrite of the scan engine only (key
// packing, butterfly merge, tie/ext logic all R2-R9 validated, unchanged):
//  - lane owns 32 CONTIGUOUS elements via 8 independent float4 loads
//    (burst-issued; vs 32 serialized stride-256B loads),
//  - BRANCH-FREE insert (cndmask chain; old `if (nk>key[7])` branched on
//    just-loaded data, forcing load->wait->branch per element),
//  - values kept in VGPRs so pass 2 runs from registers (no 2nd HBM read).
// ---------------------------------------------------------------------------
__global__ __launch_bounds__(256)
void topk_prep(const float* __restrict__ adj, const float* __restrict__ adjm,
               int* __restrict__ t_idx, float* __restrict__ t_val,
               int* __restrict__ t_cnt, float* __restrict__ t_deg,
               float* __restrict__ t_ideg, float2* __restrict__ t_sc)
{
    __shared__ int wext[4][8];
    __shared__ int wextn[4];
    const int tid = threadIdx.x;
    const int wid = tid >> 6, lane = tid & 63;
    if (lane == 0) wextn[wid] = 0;

    const int grow = blockIdx.x * 4 + wid;          // 0..3999
    const int mat = (grow >= NN) ? 1 : 0;           // 0 = adj_mask, 1 = adj
    const int row = grow - mat * NN;
    const float* src = (mat == 0 ? adjm : adj) + (size_t)row * NN;
    const float4* src4 = (const float4*)src;        // 500 float4 per row

    // ---- pass 1: load 8 float4 per lane (MLP burst), keep values live ----
    float4 v4[8];
    #pragma unroll
    for (int j = 0; j < 8; ++j) {
        const int idx4 = lane * 8 + j;
        v4[j] = (idx4 < 500) ? src4[idx4] : make_float4(0.f, 0.f, 0.f, 0.f);
    }

    unsigned long long key[8];
    #pragma unroll
    for (int j = 0; j < 8; ++j) key[j] = 0ull;

    #pragma unroll
    for (int j = 0; j < 8; ++j) {
        const float vv[4] = {v4[j].x, v4[j].y, v4[j].z, v4[j].w};
        #pragma unroll
        for (int c = 0; c < 4; ++c) {
            const unsigned e = (unsigned)((lane * 8 + j) * 4 + c);
            const unsigned long long nk =
                ((unsigned long long)__float_as_uint(vv[c]) << 32) | (unsigned)(~e);
            // branch-free sorted-top-8 insert (validated select chain)
            #pragma unroll
            for (int s = 7; s >= 1; --s)
                key[s] = (nk > key[s - 1]) ? key[s - 1] : ((nk > key[s]) ? nk : key[s]);
            if (nk > key[0]) key[0] = nk;   // compiles to cndmask (no flow dep)
        }
    }

    // ---- butterfly merge (unchanged, R2-validated) ----
    #pragma unroll
    for (int d = 1; d < 64; d <<= 1) {
        unsigned long long ok[8], c[8];
        #pragma unroll
        for (int j = 0; j < 8; ++j) ok[j] = shflx64(key[j], d);
        #pragma unroll
        for (int j = 0; j < 8; ++j) {
            unsigned long long o = ok[7 - j];
            c[j] = (key[j] > o) ? key[j] : o;
        }
        #pragma unroll
        for (int st = 4; st >= 1; st >>= 1) {
            #pragma unroll
            for (int j = 0; j < 8; ++j) {
                if ((j & st) == 0 && (j | st) < 8) {
                    unsigned long long a = c[j], b = c[j | st];
                    unsigned long long hi = (a > b) ? a : b;
                    unsigned long long lo = (a > b) ? b : a;
                    c[j] = hi; c[j | st] = lo;
                }
            }
        }
        #pragma unroll
        for (int j = 0; j < 8; ++j) key[j] = c[j];
    }

    const float thr = __uint_as_float((unsigned)(key[7] >> 32));

    // ---- pass 2: from registers (no memory). deg/cp branch-free. ----
    float degp = 0.f; int cp = 0;
    #pragma unroll
    for (int j = 0; j < 8; ++j) {
        const float vv[4] = {v4[j].x, v4[j].y, v4[j].z, v4[j].w};
        #pragma unroll
        for (int c = 0; c < 4; ++c) {
            const float v = vv[c];
            const bool ge = (v >= thr);
            degp += ge ? v : 0.f;
            cp   += (ge && v > 0.f) ? 1 : 0;
            if (v == thr) {                          // rare (~1/row)
                const unsigned e = (unsigned)((lane * 8 + j) * 4 + c);
                const unsigned long long nk =
                    ((unsigned long long)__float_as_uint(v) << 32) | (unsigned)(~e);
                if (nk < key[7]) {                   // tie beyond top-8
                    int p = atomicAdd(&wextn[wid], 1);
                    if (p < 8) wext[wid][p] = (int)e;
                }
            }
        }
    }
    #pragma unroll
    for (int off = 32; off >= 1; off >>= 1) {
        degp += __shfl_xor(degp, off, 64);
        cp   += __shfl_xor(cp, off, 64);
    }
    __syncthreads();

    if (lane == 0) {
        int en = wextn[wid]; if (en > 8) en = 8;
        const size_t ob = (size_t)grow * LISTCAP;
        #pragma unroll
        for (int j = 0; j < 8; ++j) {
            t_idx[ob + j] = (int)(~(unsigned)(key[j] & 0xffffffffull));
            t_val[ob + j] = __uint_as_float((unsigned)(key[j] >> 32));
        }
        for (int j = 0; j < 8; ++j) {
            t_idx[ob + 8 + j] = (j < en) ? wext[wid][j] : 0;
            t_val[ob + 8 + j] = (j < en) ? thr : 0.f;
        }
        t_cnt[grow]  = 8 + en;
        t_deg[grow]  = degp;
        t_ideg[grow] = 1.0f / degp;
        float s1 = log1pf((float)cp);
        t_sc[grow]   = make_float2(s1, 1.0f / s1);
    }
}

// ---------------------------------------------------------------------------
// Kernel B: stower0 + tcn0 (blocks 0..374) + weight-plane prep (375..387).
// Unchanged from R9 (validated; Theta planes pre-swizzled).
// ---------------------------------------------------------------------------
__global__ __launch_bounds__(256)
void stower0_tcn0(const float* __restrict__ X,
                  const int* __restrict__ t_idx, const float* __restrict__ t_val,
                  const int* __restrict__ t_cnt, const float* __restrict__ t_deg,
                  const float* __restrict__ Theta0, const float* __restrict__ bias0,
                  const float* __restrict__ Wt0, const float* __restrict__ bt0,
                  const float* __restrict__ Theta1, const float* __restrict__ Wt1,
                  u16* __restrict__ thHi, u16* __restrict__ thLo,
                  u16* __restrict__ wtHi, u16* __restrict__ wtLo,
                  float* __restrict__ I1)
{
    const int tid = threadIdx.x;
    if (blockIdx.x >= NSITES / 256) {
        const int pb = blockIdx.x - NSITES / 256;   // 0..12
        if (pb < 12) {                              // Theta1: 12288 elems
            const int base = pb * 1024;
            #pragma unroll
            for (int t = 0; t < 4; ++t) {
                const int i = base + t * 256 + tid;
                const int r = i >> 5, o = i & 31;
                const int jm = r >> 7, k = r & 127;
                const int tile = jm * 2 + (o >> 4), n = o & 15;
                const float v = Theta1[i];
                const u16 hi = f2bf(v);
                const int idx = (tile * 16 + n) * 128 + (((k >> 3) ^ n) << 3) + (k & 7);
                thHi[idx] = hi;
                thLo[idx] = f2bf(v - bf2f(hi));
            }
        } else {                                    // Wt1: 1024 elems
            #pragma unroll
            for (int t = 0; t < 4; ++t) {
                const int i = t * 256 + tid;
                const float v = Wt1[i];
                const u16 hi = f2bf(v);
                wtHi[i] = hi;
                wtLo[i] = f2bf(v - bf2f(hi));
            }
        }
        return;
    }

    const int site = blockIdx.x * 256 + tid;
    const int n  = site % NN;
    const int bt = site / NN;
    const float* xrow = X + (size_t)bt * NN;

    const size_t base = (size_t)n * LISTCAP;
    const int cnt   = t_cnt[n];
    const float deg = t_deg[n];
    float wsum = 0.f, wsq = 0.f, mx = -INFINITY, mn = INFINITY;
    for (int j = 0; j < cnt; ++j) {
        int   id = t_idx[base + j];
        float w  = t_val[base + j];
        float xv = xrow[id];
        wsum = fmaf(w, xv, wsum);
        wsq  = fmaf(w * xv, xv, wsq);
        if (j < KK && w > 0.f) { mx = fmaxf(mx, xv); mn = fminf(mn, xv); }
    }
    float mean = wsum / deg;
    float var  = wsq / deg - mean * mean;
    float sd   = sqrtf(fmaxf(var, 0.f) + EPSF);
    float m0 = mask6(mean), m1 = mask6(mx), m2 = mask6(mn), m3 = mask6(sd);

    float h0[CC];
    #pragma unroll
    for (int c = 0; c < CC; ++c) {
        float v = bias0[c];
        v = fmaf(m0, Theta0[0 * CC + c], v);
        v = fmaf(m1, Theta0[1 * CC + c], v);
        v = fmaf(m2, Theta0[2 * CC + c], v);
        v = fmaf(m3, Theta0[3 * CC + c], v);
        h0[c] = v;
    }
    float* op = I1 + (size_t)site * CC;
    #pragma unroll
    for (int c = 0; c < CC; ++c) {
        float acc = bt0[c] + h0[c];
        #pragma unroll
        for (int k = 0; k < CC; ++k) acc = fmaf(Wt0[c * CC + k], h0[k], acc);
        op[c] = tanhf(acc);
    }
}

// ---------------------------------------------------------------------------
// Kernel C1: stower1 aggregation, swizzled A-frag global writes
// (unchanged from R9 — validated).
// ---------------------------------------------------------------------------
__global__ __launch_bounds__(256)
void stower1_agg(const float* __restrict__ I1,
                 const int* __restrict__ t_idx, const float* __restrict__ t_val,
                 const int* __restrict__ t_cnt, const float* __restrict__ t_ideg,
                 u16* __restrict__ mHi, u16* __restrict__ mLo)
{
    const int tid  = threadIdx.x;
    const int site = blockIdx.x * 8 + (tid >> 5);   // 12000 blocks x 8 sites
    const int f    = tid & 31;
    const int n  = site % NN;
    const int bt = site / NN;
    const size_t rbase = (size_t)(NN + n) * LISTCAP;
    const int cnt    = t_cnt[NN + n];
    const float ideg = t_ideg[NN + n];
    const float* Ibt = I1 + (size_t)bt * NN * CC;

    const int4   i0 = *(const int4*)&t_idx[rbase];
    const int4   i1 = *(const int4*)&t_idx[rbase + 4];
    const float4 w0 = *(const float4*)&t_val[rbase];
    const float4 w1 = *(const float4*)&t_val[rbase + 4];

    const float x0 = Ibt[(size_t)i0.x * CC + f];
    const float x1 = Ibt[(size_t)i0.y * CC + f];
    const float x2 = Ibt[(size_t)i0.z * CC + f];
    const float x3 = Ibt[(size_t)i0.w * CC + f];
    const float x4 = Ibt[(size_t)i1.x * CC + f];
    const float x5 = Ibt[(size_t)i1.y * CC + f];
    const float x6 = Ibt[(size_t)i1.z * CC + f];
    const float x7 = Ibt[(size_t)i1.w * CC + f];

    float wsum = 0.f, wsq = 0.f, mx = -INFINITY, mn = INFINITY;
    #define AGG(wv, xv) do { \
        wsum = fmaf(wv, xv, wsum); wsq = fmaf(wv * xv, xv, wsq); \
        mx = fmaxf(mx, xv); mn = fminf(mn, xv); } while (0)
    AGG(w0.x, x0); AGG(w0.y, x1); AGG(w0.z, x2); AGG(w0.w, x3);
    AGG(w1.x, x4); AGG(w1.y, x5); AGG(w1.z, x6); AGG(w1.w, x7);
    #undef AGG
    if (cnt > 8) {                    // tie extras: ~never taken
        for (int j = 8; j < cnt; ++j) {
            int   id = t_idx[rbase + j];
            float wv = t_val[rbase + j];
            float xv = Ibt[(size_t)id * CC + f];
            wsum = fmaf(wv, xv, wsum);
            wsq  = fmaf(wv * xv, xv, wsq);
        }
    }
    const float mean = wsum * ideg;
    const float var  = wsq * ideg - mean * mean;
    const float sd   = sqrtf(fmaxf(var, 0.f) + EPSF);

    const int sx = site & 15;
    const int b  = site * 128;
    const int fh = f >> 3, fl = f & 7;
    const int ia  = b + (((0  + fh) ^ sx) << 3) + fl;   // k = f
    const int ib  = b + (((4  + fh) ^ sx) << 3) + fl;   // k = 32+f
    const int ic  = b + (((8  + fh) ^ sx) << 3) + fl;   // k = 64+f
    const int id_ = b + (((12 + fh) ^ sx) << 3) + fl;   // k = 96+f
    u16 h0 = f2bf(mean); mHi[ia]  = h0; mLo[ia]  = f2bf(mean - bf2f(h0));
    u16 h1 = f2bf(mx);   mHi[ib]  = h1; mLo[ib]  = f2bf(mx   - bf2f(h1));
    u16 h2 = f2bf(mn);   mHi[ic]  = h2; mLo[ic]  = f2bf(mn   - bf2f(h2));
    u16 h3 = f2bf(sd);   mHi[id_] = h3; mLo[id_] = f2bf(sd   - bf2f(h3));
}

// ---------------------------------------------------------------------------
// Kernel C2: stower1 matmul + tcn1 + Wout (unchanged from R9 — validated;
// LDS-memcpy staging pattern, 1000 blocks x 3 macros).
// ---------------------------------------------------------------------------
__global__ __launch_bounds__(256, 3)
void stower1_gemm(const u16* __restrict__ mHi, const u16* __restrict__ mLo,
                  const u16* __restrict__ thHi, const u16* __restrict__ thLo,
                  const u16* __restrict__ wtHi, const u16* __restrict__ wtLo,
                  const float2* __restrict__ t_sc,
                  const float* __restrict__ bias1, const float* __restrict__ bt1,
                  const float* __restrict__ Wout, const float* __restrict__ bout,
                  float* __restrict__ out)
{
    __shared__ u16 sBlo[96 * 128];                  // 24 KiB: Theta-lo (swizzled)
    __shared__ alignas(16) u16 uSpace[12288];       // 24 KiB: thHi stage | m tile | h
    __shared__ float sPart[64];

    u16*   mT  = uSpace;                            // m tile: [0..4095]=hi, [4096..8191]=lo
    u16*   hHi = uSpace;                            // 32*40 u16
    u16*   hLo = hHi + 32 * 40;
    float* h32 = (float*)((char*)uSpace + 5120);    // 32*33 f32

    const int tid  = threadIdx.x;
    const int lane = tid & 63;
    const int w    = tid >> 6;
    const int m15  = lane & 15;
    const int q    = lane >> 4;
    const int hf   = w & 1;          // phase-2 out-channel half
    const int st   = w >> 1;         // phase-2 site-tile 0..1
    const int ot   = w >> 1;         // phase-3 tcn out-tile
    const int st2  = w & 1;          // phase-3 site-tile

    // ---- init 1: memcpy thHi (24 KB, pre-swizzled) -> uSpace, extract ----
    for (int i = tid; i < 1536; i += 256)
        ((float4*)uSpace)[i] = ((const float4*)thHi)[i];
    __syncthreads();
    bf16x8 bH[3][4];
    #pragma unroll
    for (int j3 = 0; j3 < 3; ++j3) {
        const int tile = 2 * j3 + hf;
        #pragma unroll
        for (int ks = 0; ks < 4; ++ks)
            bH[j3][ks] = *(const bf16x8*)&uSpace[(tile * 16 + m15) * 128 +
                                                 (((ks * 4 + q) ^ m15) << 3)];
    }
    __syncthreads();
    // ---- init 2: memcpy thLo (pre-swizzled) -> sBlo; wt frags; scalars ----
    for (int i = tid; i < 1536; i += 256)
        ((float4*)sBlo)[i] = ((const float4*)thLo)[i];
    const bf16x8 bwh = *(const bf16x8*)&wtHi[(ot * 16 + m15) * 32 + q * 8];
    const bf16x8 bwl = *(const bf16x8*)&wtLo[(ot * 16 + m15) * 32 + q * 8];
    const float b1o   = bias1[hf * 16 + m15];
    const float bt1o  = bt1[ot * 16 + m15];
    const float wouto = Wout[ot * 16 + m15];
    const float boutv = bout[0];
    // no sync here: the sync after the first m-stage orders sBlo too.

    #pragma unroll 1
    for (int mb = 0; mb < 3; ++mb) {
        const int sbase = (blockIdx.x * 3 + mb) * 32;

        // ---- phase 1: memcpy m tile (16 KB) -> LDS (burst-friendly) ----
        {
            const float4* gh = (const float4*)&mHi[(size_t)sbase * 128];
            const float4* gl = (const float4*)&mLo[(size_t)sbase * 128];
            float4* dh = (float4*)mT;               // 512 float4
            float4* dl = (float4*)(mT + 4096);      // 512 float4
            dh[tid]       = gh[tid];
            dh[tid + 256] = gh[tid + 256];
            dl[tid]       = gl[tid];
            dl[tid + 256] = gl[tid + 256];
        }
        __syncthreads();

        // ---- phase 2: MFMA (A from LDS m tile, B hi regs / lo LDS) ----
        f32x4 acc[3];
        #pragma unroll
        for (int j3 = 0; j3 < 3; ++j3) acc[j3] = (f32x4){0.f, 0.f, 0.f, 0.f};
        const int arow = (st * 16 + m15) * 128;
        #pragma unroll
        for (int ks = 0; ks < 4; ++ks) {
            const int koff = (((ks * 4 + q) ^ m15) << 3);
            const bf16x8 aH = *(const bf16x8*)&mT[arow + koff];
            const bf16x8 aL = *(const bf16x8*)&mT[4096 + arow + koff];
            #pragma unroll
            for (int j3 = 0; j3 < 3; ++j3) {
                const bf16x8 bL = *(const bf16x8*)&sBlo[((2 * j3 + hf) * 16 + m15) * 128 + koff];
                acc[j3] = __builtin_amdgcn_mfma_f32_16x16x32_bf16(aH, bH[j3][ks], acc[j3], 0, 0, 0);
                acc[j3] = __builtin_amdgcn_mfma_f32_16x16x32_bf16(aH, bL,          acc[j3], 0, 0, 0);
                acc[j3] = __builtin_amdgcn_mfma_f32_16x16x32_bf16(aL, bH[j3][ks], acc[j3], 0, 0, 0);
            }
        }
        __syncthreads();   // all m-tile reads done -> safe to alias h

        // ---- combine scalers -> h (split-bf16 + f32 residual) ----
        #pragma unroll
        for (int r = 0; r < 4; ++r) {
            const int sl2  = st * 16 + q * 4 + r;
            const int site = sbase + sl2;
            const int n    = site % NN;
            const float2 sc = t_sc[NN + n];
            float h = acc[0][r] + sc.x * acc[1][r] + sc.y * acc[2][r] + b1o;
            h = fmaxf(h, 0.f);
            const int o = hf * 16 + m15;
            const u16 hi = f2bf(h);
            hHi[sl2 * 40 + o] = hi;
            hLo[sl2 * 40 + o] = f2bf(h - bf2f(hi));
            h32[sl2 * 33 + o] = h;
        }
        __syncthreads();

        // ---- phase 3: tcn1 via MFMA + Wout lane-reduce (R4 exact) ----
        f32x4 c2 = (f32x4){0.f, 0.f, 0.f, 0.f};
        {
            const bf16x8 ahh = *(const bf16x8*)&hHi[(st2 * 16 + m15) * 40 + q * 8];
            const bf16x8 ahl = *(const bf16x8*)&hLo[(st2 * 16 + m15) * 40 + q * 8];
            c2 = __builtin_amdgcn_mfma_f32_16x16x32_bf16(ahh, bwh, c2, 0, 0, 0);
            c2 = __builtin_amdgcn_mfma_f32_16x16x32_bf16(ahh, bwl, c2, 0, 0, 0);
            c2 = __builtin_amdgcn_mfma_f32_16x16x32_bf16(ahl, bwh, c2, 0, 0, 0);
        }
        float p[4];
        #pragma unroll
        for (int r = 0; r < 4; ++r) {
            const int sl2 = st2 * 16 + q * 4 + r;
            const float hres = h32[sl2 * 33 + ot * 16 + m15];
            float yv = tanhf(c2[r] + bt1o + hres);
            yv = fmaxf(yv, 0.f);
            p[r] = yv * wouto;
            #pragma unroll
            for (int mk = 1; mk <= 8; mk <<= 1)
                p[r] += __shfl_xor(p[r], mk, 64);
        }
        float selv  = (m15 & 1) ? p[1] : p[0];
        float selv2 = (m15 & 1) ? p[3] : p[2];
        selv = (m15 & 2) ? selv2 : selv;
        if (m15 < 4) sPart[ot * 32 + st2 * 16 + q * 4 + m15] = selv;
        __syncthreads();

        if (tid < 32) out[sbase + tid] = sPart[tid] + sPart[32 + tid] + boutv;
        // no trailing sync (R4-validated): next macro's LDS writes are to
        // uSpace, whose readers (phase-3 h reads) precede the sync above;
        // sPart is rewritten only after 3 more syncs.
    }
}

// ---------------------------------------------------------------------------
extern "C" void kernel_launch(void* const* d_in, const int* in_sizes, int n_in,
                              void* d_out, int out_size, void* d_ws, size_t ws_size,
                              hipStream_t stream)
{
    const float* X      = (const float*)d_in[0];
    const float* adj    = (const float*)d_in[1];
    const float* adjm   = (const float*)d_in[2];
    const float* Theta0 = (const float*)d_in[3];
    const float* bias0  = (const float*)d_in[4];
    const float* Wt0    = (const float*)d_in[5];
    const float* bt0    = (const float*)d_in[6];
    const float* Theta1 = (const float*)d_in[7];
    const float* bias1  = (const float*)d_in[8];
    const float* Wt1    = (const float*)d_in[9];
    const float* bt1    = (const float*)d_in[10];
    const float* Wout   = (const float*)d_in[11];
    const float* bout   = (const float*)d_in[12];
    (void)in_sizes; (void)n_in; (void)out_size; (void)ws_size;

    char* p = (char*)d_ws;
    int*    t_idx  = (int*)p;    p += (size_t)2 * NN * LISTCAP * sizeof(int);
    float*  t_val  = (float*)p;  p += (size_t)2 * NN * LISTCAP * sizeof(float);
    int*    t_cnt  = (int*)p;    p += (size_t)2 * NN * sizeof(int);
    float*  t_deg  = (float*)p;  p += (size_t)2 * NN * sizeof(float);
    float*  t_ideg = (float*)p;  p += (size_t)2 * NN * sizeof(float);
    float2* t_sc   = (float2*)p; p += (size_t)2 * NN * sizeof(float2);
    float*  I1     = (float*)p;  p += (size_t)NSITES * CC * sizeof(float);
    u16*    mHi    = (u16*)p;    p += (size_t)NSITES * 128 * sizeof(u16);
    u16*    mLo    = (u16*)p;    p += (size_t)NSITES * 128 * sizeof(u16);
    u16*    thHi   = (u16*)p;    p += (size_t)96 * 128 * sizeof(u16);
    u16*    thLo   = (u16*)p;    p += (size_t)96 * 128 * sizeof(u16);
    u16*    wtHi   = (u16*)p;    p += (size_t)1024 * sizeof(u16);
    u16*    wtLo   = (u16*)p;    p += (size_t)1024 * sizeof(u16);

    hipLaunchKernelGGL(topk_prep, dim3(2 * NN / 4), dim3(256), 0, stream,
                       adj, adjm, t_idx, t_val, t_cnt, t_deg, t_ideg, t_sc);
    hipLaunchKernelGGL(stower0_tcn0, dim3(NSITES / 256 + 13), dim3(256), 0, stream,
                       X, t_idx, t_val, t_cnt, t_deg, Theta0, bias0, Wt0, bt0,
                       Theta1, Wt1, thHi, thLo, wtHi, wtLo, I1);
    hipLaunchKernelGGL(stower1_agg, dim3(NSITES / 8), dim3(256), 0, stream,
                       I1, t_idx, t_val, t_cnt, t_ideg, mHi, mLo);
    hipLaunchKernelGGL(stower1_gemm, dim3(NSITES / 96), dim3(256), 0, stream,
                       mHi, mLo, thHi, thLo, wtHi, wtLo, t_sc,
                       bias1, bt1, Wout, bout, (float*)d_out);
}

// Round 11
// 183.566 us; speedup vs baseline: 1.0836x; 1.0836x over previous
//
#include <hip/hip_runtime.h>
#include <hip/hip_bf16.h>
#include <math.h>

#define BB 4
#define TT 12
#define NN 2000
#define KK 8
#define CC 32
#define EPSF 1e-5f
#define LISTCAP 16
#define NSITES (BB * TT * NN)   // 96000

typedef unsigned short u16;
typedef __bf16 bf16x8 __attribute__((ext_vector_type(8)));
typedef float  f32x4  __attribute__((ext_vector_type(4)));

__device__ __forceinline__ u16 f2bf(float x) {
    union { __hip_bfloat16 h; u16 u; } c;
    c.h = __float2bfloat16(x);   // RNE
    return c.u;
}
__device__ __forceinline__ float bf2f(u16 u) {
    return __uint_as_float(((unsigned)u) << 16);
}
__device__ __forceinline__ float mask6(float v) {
    if (isnan(v)) v = 6.0f;
    if (isinf(v)) v = 0.0f;
    return fminf(v, 6.0f);
}
__device__ __forceinline__ unsigned long long shflx64(unsigned long long v, int m) {
    int lo = __shfl_xor((int)(unsigned)(v & 0xffffffffull), m, 64);
    int hi = __shfl_xor((int)(unsigned)(v >> 32), m, 64);
    return ((unsigned long long)(unsigned)hi << 32) | (unsigned)lo;
}

// ---------------------------------------------------------------------------
// Kernel A: wave-per-row top-K. R11 fix over R10: INTERLEAVED float4
// ownership (idx4 = j*64 + lane) -> each of the 8 loads is a perfectly
// coalesced 1 KB wave transaction (R10's lane-contiguous layout strided
// lanes 128 B apart: 64 lines/instr, FETCH_SIZE 68 MB, L1 thrash).
// Branch-free insert + register-resident pass 2 kept (R10-validated).
// ---------------------------------------------------------------------------
__global__ __launch_bounds__(256)
void topk_prep(const float* __restrict__ adj, const float* __restrict__ adjm,
               int* __restrict__ t_idx, float* __restrict__ t_val,
               int* __restrict__ t_cnt, float* __restrict__ t_deg,
               float* __restrict__ t_ideg, float2* __restrict__ t_sc)
{
    __shared__ int wext[4][8];
    __shared__ int wextn[4];
    const int tid = threadIdx.x;
    const int wid = tid >> 6, lane = tid & 63;
    if (lane == 0) wextn[wid] = 0;

    const int grow = blockIdx.x * 4 + wid;          // 0..3999
    const int mat = (grow >= NN) ? 1 : 0;           // 0 = adj_mask, 1 = adj
    const int row = grow - mat * NN;
    const float* src = (mat == 0 ? adjm : adj) + (size_t)row * NN;
    const float4* src4 = (const float4*)src;        // 500 float4 per row

    // ---- pass 1: 8 coalesced float4 wave-loads, values stay in VGPRs ----
    float4 v4[8];
    #pragma unroll
    for (int j = 0; j < 8; ++j) {
        const int idx4 = j * 64 + lane;             // consecutive lanes adjacent
        v4[j] = (idx4 < 500) ? src4[idx4] : make_float4(0.f, 0.f, 0.f, 0.f);
    }

    unsigned long long key[8];
    #pragma unroll
    for (int j = 0; j < 8; ++j) key[j] = 0ull;

    #pragma unroll
    for (int j = 0; j < 8; ++j) {
        const float vv[4] = {v4[j].x, v4[j].y, v4[j].z, v4[j].w};
        #pragma unroll
        for (int c = 0; c < 4; ++c) {
            const unsigned e = (unsigned)((j * 64 + lane) * 4 + c);
            const unsigned long long nk =
                ((unsigned long long)__float_as_uint(vv[c]) << 32) | (unsigned)(~e);
            // branch-free sorted-top-8 insert (R10-validated select chain)
            #pragma unroll
            for (int s = 7; s >= 1; --s)
                key[s] = (nk > key[s - 1]) ? key[s - 1] : ((nk > key[s]) ? nk : key[s]);
            if (nk > key[0]) key[0] = nk;   // compiles to cndmask
        }
    }

    // ---- butterfly merge (unchanged, R2-validated) ----
    #pragma unroll
    for (int d = 1; d < 64; d <<= 1) {
        unsigned long long ok[8], c[8];
        #pragma unroll
        for (int j = 0; j < 8; ++j) ok[j] = shflx64(key[j], d);
        #pragma unroll
        for (int j = 0; j < 8; ++j) {
            unsigned long long o = ok[7 - j];
            c[j] = (key[j] > o) ? key[j] : o;
        }
        #pragma unroll
        for (int st = 4; st >= 1; st >>= 1) {
            #pragma unroll
            for (int j = 0; j < 8; ++j) {
                if ((j & st) == 0 && (j | st) < 8) {
                    unsigned long long a = c[j], b = c[j | st];
                    unsigned long long hi = (a > b) ? a : b;
                    unsigned long long lo = (a > b) ? b : a;
                    c[j] = hi; c[j | st] = lo;
                }
            }
        }
        #pragma unroll
        for (int j = 0; j < 8; ++j) key[j] = c[j];
    }

    const float thr = __uint_as_float((unsigned)(key[7] >> 32));

    // ---- pass 2: from registers (no memory). deg/cp branch-free. ----
    float degp = 0.f; int cp = 0;
    #pragma unroll
    for (int j = 0; j < 8; ++j) {
        const float vv[4] = {v4[j].x, v4[j].y, v4[j].z, v4[j].w};
        #pragma unroll
        for (int c = 0; c < 4; ++c) {
            const float v = vv[c];
            const bool ge = (v >= thr);
            degp += ge ? v : 0.f;
            cp   += (ge && v > 0.f) ? 1 : 0;
            if (v == thr) {                          // rare (~1/row)
                const unsigned e = (unsigned)((j * 64 + lane) * 4 + c);
                const unsigned long long nk =
                    ((unsigned long long)__float_as_uint(v) << 32) | (unsigned)(~e);
                if (nk < key[7]) {                   // tie beyond top-8
                    int p = atomicAdd(&wextn[wid], 1);
                    if (p < 8) wext[wid][p] = (int)e;
                }
            }
        }
    }
    #pragma unroll
    for (int off = 32; off >= 1; off >>= 1) {
        degp += __shfl_xor(degp, off, 64);
        cp   += __shfl_xor(cp, off, 64);
    }
    __syncthreads();

    if (lane == 0) {
        int en = wextn[wid]; if (en > 8) en = 8;
        const size_t ob = (size_t)grow * LISTCAP;
        #pragma unroll
        for (int j = 0; j < 8; ++j) {
            t_idx[ob + j] = (int)(~(unsigned)(key[j] & 0xffffffffull));
            t_val[ob + j] = __uint_as_float((unsigned)(key[j] >> 32));
        }
        for (int j = 0; j < 8; ++j) {
            t_idx[ob + 8 + j] = (j < en) ? wext[wid][j] : 0;
            t_val[ob + 8 + j] = (j < en) ? thr : 0.f;
        }
        t_cnt[grow]  = 8 + en;
        t_deg[grow]  = degp;
        t_ideg[grow] = 1.0f / degp;
        float s1 = log1pf((float)cp);
        t_sc[grow]   = make_float2(s1, 1.0f / s1);
    }
}

// ---------------------------------------------------------------------------
// Kernel B: stower0 + tcn0 (blocks 0..374) + weight-plane prep (375..387).
// Unchanged from R9 (validated; Theta planes pre-swizzled).
// ---------------------------------------------------------------------------
__global__ __launch_bounds__(256)
void stower0_tcn0(const float* __restrict__ X,
                  const int* __restrict__ t_idx, const float* __restrict__ t_val,
                  const int* __restrict__ t_cnt, const float* __restrict__ t_deg,
                  const float* __restrict__ Theta0, const float* __restrict__ bias0,
                  const float* __restrict__ Wt0, const float* __restrict__ bt0,
                  const float* __restrict__ Theta1, const float* __restrict__ Wt1,
                  u16* __restrict__ thHi, u16* __restrict__ thLo,
                  u16* __restrict__ wtHi, u16* __restrict__ wtLo,
                  float* __restrict__ I1)
{
    const int tid = threadIdx.x;
    if (blockIdx.x >= NSITES / 256) {
        const int pb = blockIdx.x - NSITES / 256;   // 0..12
        if (pb < 12) {                              // Theta1: 12288 elems
            const int base = pb * 1024;
            #pragma unroll
            for (int t = 0; t < 4; ++t) {
                const int i = base + t * 256 + tid;
                const int r = i >> 5, o = i & 31;
                const int jm = r >> 7, k = r & 127;
                const int tile = jm * 2 + (o >> 4), n = o & 15;
                const float v = Theta1[i];
                const u16 hi = f2bf(v);
                const int idx = (tile * 16 + n) * 128 + (((k >> 3) ^ n) << 3) + (k & 7);
                thHi[idx] = hi;
                thLo[idx] = f2bf(v - bf2f(hi));
            }
        } else {                                    // Wt1: 1024 elems
            #pragma unroll
            for (int t = 0; t < 4; ++t) {
                const int i = t * 256 + tid;
                const float v = Wt1[i];
                const u16 hi = f2bf(v);
                wtHi[i] = hi;
                wtLo[i] = f2bf(v - bf2f(hi));
            }
        }
        return;
    }

    const int site = blockIdx.x * 256 + tid;
    const int n  = site % NN;
    const int bt = site / NN;
    const float* xrow = X + (size_t)bt * NN;

    const size_t base = (size_t)n * LISTCAP;
    const int cnt   = t_cnt[n];
    const float deg = t_deg[n];
    float wsum = 0.f, wsq = 0.f, mx = -INFINITY, mn = INFINITY;
    for (int j = 0; j < cnt; ++j) {
        int   id = t_idx[base + j];
        float w  = t_val[base + j];
        float xv = xrow[id];
        wsum = fmaf(w, xv, wsum);
        wsq  = fmaf(w * xv, xv, wsq);
        if (j < KK && w > 0.f) { mx = fmaxf(mx, xv); mn = fminf(mn, xv); }
    }
    float mean = wsum / deg;
    float var  = wsq / deg - mean * mean;
    float sd   = sqrtf(fmaxf(var, 0.f) + EPSF);
    float m0 = mask6(mean), m1 = mask6(mx), m2 = mask6(mn), m3 = mask6(sd);

    float h0[CC];
    #pragma unroll
    for (int c = 0; c < CC; ++c) {
        float v = bias0[c];
        v = fmaf(m0, Theta0[0 * CC + c], v);
        v = fmaf(m1, Theta0[1 * CC + c], v);
        v = fmaf(m2, Theta0[2 * CC + c], v);
        v = fmaf(m3, Theta0[3 * CC + c], v);
        h0[c] = v;
    }
    float* op = I1 + (size_t)site * CC;
    #pragma unroll
    for (int c = 0; c < CC; ++c) {
        float acc = bt0[c] + h0[c];
        #pragma unroll
        for (int k = 0; k < CC; ++k) acc = fmaf(Wt0[c * CC + k], h0[k], acc);
        op[c] = tanhf(acc);
    }
}

// ---------------------------------------------------------------------------
// Kernel C1: stower1 aggregation, swizzled A-frag global writes
// (unchanged from R9 — validated).
// ---------------------------------------------------------------------------
__global__ __launch_bounds__(256)
void stower1_agg(const float* __restrict__ I1,
                 const int* __restrict__ t_idx, const float* __restrict__ t_val,
                 const int* __restrict__ t_cnt, const float* __restrict__ t_ideg,
                 u16* __restrict__ mHi, u16* __restrict__ mLo)
{
    const int tid  = threadIdx.x;
    const int site = blockIdx.x * 8 + (tid >> 5);   // 12000 blocks x 8 sites
    const int f    = tid & 31;
    const int n  = site % NN;
    const int bt = site / NN;
    const size_t rbase = (size_t)(NN + n) * LISTCAP;
    const int cnt    = t_cnt[NN + n];
    const float ideg = t_ideg[NN + n];
    const float* Ibt = I1 + (size_t)bt * NN * CC;

    const int4   i0 = *(const int4*)&t_idx[rbase];
    const int4   i1 = *(const int4*)&t_idx[rbase + 4];
    const float4 w0 = *(const float4*)&t_val[rbase];
    const float4 w1 = *(const float4*)&t_val[rbase + 4];

    const float x0 = Ibt[(size_t)i0.x * CC + f];
    const float x1 = Ibt[(size_t)i0.y * CC + f];
    const float x2 = Ibt[(size_t)i0.z * CC + f];
    const float x3 = Ibt[(size_t)i0.w * CC + f];
    const float x4 = Ibt[(size_t)i1.x * CC + f];
    const float x5 = Ibt[(size_t)i1.y * CC + f];
    const float x6 = Ibt[(size_t)i1.z * CC + f];
    const float x7 = Ibt[(size_t)i1.w * CC + f];

    float wsum = 0.f, wsq = 0.f, mx = -INFINITY, mn = INFINITY;
    #define AGG(wv, xv) do { \
        wsum = fmaf(wv, xv, wsum); wsq = fmaf(wv * xv, xv, wsq); \
        mx = fmaxf(mx, xv); mn = fminf(mn, xv); } while (0)
    AGG(w0.x, x0); AGG(w0.y, x1); AGG(w0.z, x2); AGG(w0.w, x3);
    AGG(w1.x, x4); AGG(w1.y, x5); AGG(w1.z, x6); AGG(w1.w, x7);
    #undef AGG
    if (cnt > 8) {                    // tie extras: ~never taken
        for (int j = 8; j < cnt; ++j) {
            int   id = t_idx[rbase + j];
            float wv = t_val[rbase + j];
            float xv = Ibt[(size_t)id * CC + f];
            wsum = fmaf(wv, xv, wsum);
            wsq  = fmaf(wv * xv, xv, wsq);
        }
    }
    const float mean = wsum * ideg;
    const float var  = wsq * ideg - mean * mean;
    const float sd   = sqrtf(fmaxf(var, 0.f) + EPSF);

    const int sx = site & 15;
    const int b  = site * 128;
    const int fh = f >> 3, fl = f & 7;
    const int ia  = b + (((0  + fh) ^ sx) << 3) + fl;   // k = f
    const int ib  = b + (((4  + fh) ^ sx) << 3) + fl;   // k = 32+f
    const int ic  = b + (((8  + fh) ^ sx) << 3) + fl;   // k = 64+f
    const int id_ = b + (((12 + fh) ^ sx) << 3) + fl;   // k = 96+f
    u16 h0 = f2bf(mean); mHi[ia]  = h0; mLo[ia]  = f2bf(mean - bf2f(h0));
    u16 h1 = f2bf(mx);   mHi[ib]  = h1; mLo[ib]  = f2bf(mx   - bf2f(h1));
    u16 h2 = f2bf(mn);   mHi[ic]  = h2; mLo[ic]  = f2bf(mn   - bf2f(h2));
    u16 h3 = f2bf(sd);   mHi[id_] = h3; mLo[id_] = f2bf(sd   - bf2f(h3));
}

// ---------------------------------------------------------------------------
// Kernel C2: stower1 matmul + tcn1 + Wout (unchanged from R9 — validated;
// LDS-memcpy staging pattern, 1000 blocks x 3 macros).
// ---------------------------------------------------------------------------
__global__ __launch_bounds__(256, 3)
void stower1_gemm(const u16* __restrict__ mHi, const u16* __restrict__ mLo,
                  const u16* __restrict__ thHi, const u16* __restrict__ thLo,
                  const u16* __restrict__ wtHi, const u16* __restrict__ wtLo,
                  const float2* __restrict__ t_sc,
                  const float* __restrict__ bias1, const float* __restrict__ bt1,
                  const float* __restrict__ Wout, const float* __restrict__ bout,
                  float* __restrict__ out)
{
    __shared__ u16 sBlo[96 * 128];                  // 24 KiB: Theta-lo (swizzled)
    __shared__ alignas(16) u16 uSpace[12288];       // 24 KiB: thHi stage | m tile | h
    __shared__ float sPart[64];

    u16*   mT  = uSpace;                            // m tile: [0..4095]=hi, [4096..8191]=lo
    u16*   hHi = uSpace;                            // 32*40 u16
    u16*   hLo = hHi + 32 * 40;
    float* h32 = (float*)((char*)uSpace + 5120);    // 32*33 f32

    const int tid  = threadIdx.x;
    const int lane = tid & 63;
    const int w    = tid >> 6;
    const int m15  = lane & 15;
    const int q    = lane >> 4;
    const int hf   = w & 1;          // phase-2 out-channel half
    const int st   = w >> 1;         // phase-2 site-tile 0..1
    const int ot   = w >> 1;         // phase-3 tcn out-tile
    const int st2  = w & 1;          // phase-3 site-tile

    // ---- init 1: memcpy thHi (24 KB, pre-swizzled) -> uSpace, extract ----
    for (int i = tid; i < 1536; i += 256)
        ((float4*)uSpace)[i] = ((const float4*)thHi)[i];
    __syncthreads();
    bf16x8 bH[3][4];
    #pragma unroll
    for (int j3 = 0; j3 < 3; ++j3) {
        const int tile = 2 * j3 + hf;
        #pragma unroll
        for (int ks = 0; ks < 4; ++ks)
            bH[j3][ks] = *(const bf16x8*)&uSpace[(tile * 16 + m15) * 128 +
                                                 (((ks * 4 + q) ^ m15) << 3)];
    }
    __syncthreads();
    // ---- init 2: memcpy thLo (pre-swizzled) -> sBlo; wt frags; scalars ----
    for (int i = tid; i < 1536; i += 256)
        ((float4*)sBlo)[i] = ((const float4*)thLo)[i];
    const bf16x8 bwh = *(const bf16x8*)&wtHi[(ot * 16 + m15) * 32 + q * 8];
    const bf16x8 bwl = *(const bf16x8*)&wtLo[(ot * 16 + m15) * 32 + q * 8];
    const float b1o   = bias1[hf * 16 + m15];
    const float bt1o  = bt1[ot * 16 + m15];
    const float wouto = Wout[ot * 16 + m15];
    const float boutv = bout[0];
    // no sync here: the sync after the first m-stage orders sBlo too.

    #pragma unroll 1
    for (int mb = 0; mb < 3; ++mb) {
        const int sbase = (blockIdx.x * 3 + mb) * 32;

        // ---- phase 1: memcpy m tile (16 KB) -> LDS (burst-friendly) ----
        {
            const float4* gh = (const float4*)&mHi[(size_t)sbase * 128];
            const float4* gl = (const float4*)&mLo[(size_t)sbase * 128];
            float4* dh = (float4*)mT;               // 512 float4
            float4* dl = (float4*)(mT + 4096);      // 512 float4
            dh[tid]       = gh[tid];
            dh[tid + 256] = gh[tid + 256];
            dl[tid]       = gl[tid];
            dl[tid + 256] = gl[tid + 256];
        }
        __syncthreads();

        // ---- phase 2: MFMA (A from LDS m tile, B hi regs / lo LDS) ----
        f32x4 acc[3];
        #pragma unroll
        for (int j3 = 0; j3 < 3; ++j3) acc[j3] = (f32x4){0.f, 0.f, 0.f, 0.f};
        const int arow = (st * 16 + m15) * 128;
        #pragma unroll
        for (int ks = 0; ks < 4; ++ks) {
            const int koff = (((ks * 4 + q) ^ m15) << 3);
            const bf16x8 aH = *(const bf16x8*)&mT[arow + koff];
            const bf16x8 aL = *(const bf16x8*)&mT[4096 + arow + koff];
            #pragma unroll
            for (int j3 = 0; j3 < 3; ++j3) {
                const bf16x8 bL = *(const bf16x8*)&sBlo[((2 * j3 + hf) * 16 + m15) * 128 + koff];
                acc[j3] = __builtin_amdgcn_mfma_f32_16x16x32_bf16(aH, bH[j3][ks], acc[j3], 0, 0, 0);
                acc[j3] = __builtin_amdgcn_mfma_f32_16x16x32_bf16(aH, bL,          acc[j3], 0, 0, 0);
                acc[j3] = __builtin_amdgcn_mfma_f32_16x16x32_bf16(aL, bH[j3][ks], acc[j3], 0, 0, 0);
            }
        }
        __syncthreads();   // all m-tile reads done -> safe to alias h

        // ---- combine scalers -> h (split-bf16 + f32 residual) ----
        #pragma unroll
        for (int r = 0; r < 4; ++r) {
            const int sl2  = st * 16 + q * 4 + r;
            const int site = sbase + sl2;
            const int n    = site % NN;
            const float2 sc = t_sc[NN + n];
            float h = acc[0][r] + sc.x * acc[1][r] + sc.y * acc[2][r] + b1o;
            h = fmaxf(h, 0.f);
            const int o = hf * 16 + m15;
            const u16 hi = f2bf(h);
            hHi[sl2 * 40 + o] = hi;
            hLo[sl2 * 40 + o] = f2bf(h - bf2f(hi));
            h32[sl2 * 33 + o] = h;
        }
        __syncthreads();

        // ---- phase 3: tcn1 via MFMA + Wout lane-reduce (R4 exact) ----
        f32x4 c2 = (f32x4){0.f, 0.f, 0.f, 0.f};
        {
            const bf16x8 ahh = *(const bf16x8*)&hHi[(st2 * 16 + m15) * 40 + q * 8];
            const bf16x8 ahl = *(const bf16x8*)&hLo[(st2 * 16 + m15) * 40 + q * 8];
            c2 = __builtin_amdgcn_mfma_f32_16x16x32_bf16(ahh, bwh, c2, 0, 0, 0);
            c2 = __builtin_amdgcn_mfma_f32_16x16x32_bf16(ahh, bwl, c2, 0, 0, 0);
            c2 = __builtin_amdgcn_mfma_f32_16x16x32_bf16(ahl, bwh, c2, 0, 0, 0);
        }
        float p[4];
        #pragma unroll
        for (int r = 0; r < 4; ++r) {
            const int sl2 = st2 * 16 + q * 4 + r;
            const float hres = h32[sl2 * 33 + ot * 16 + m15];
            float yv = tanhf(c2[r] + bt1o + hres);
            yv = fmaxf(yv, 0.f);
            p[r] = yv * wouto;
            #pragma unroll
            for (int mk = 1; mk <= 8; mk <<= 1)
                p[r] += __shfl_xor(p[r], mk, 64);
        }
        float selv  = (m15 & 1) ? p[1] : p[0];
        float selv2 = (m15 & 1) ? p[3] : p[2];
        selv = (m15 & 2) ? selv2 : selv;
        if (m15 < 4) sPart[ot * 32 + st2 * 16 + q * 4 + m15] = selv;
        __syncthreads();

        if (tid < 32) out[sbase + tid] = sPart[tid] + sPart[32 + tid] + boutv;
        // no trailing sync (R4-validated): next macro's LDS writes are to
        // uSpace, whose readers (phase-3 h reads) precede the sync above;
        // sPart is rewritten only after 3 more syncs.
    }
}

// ---------------------------------------------------------------------------
extern "C" void kernel_launch(void* const* d_in, const int* in_sizes, int n_in,
                              void* d_out, int out_size, void* d_ws, size_t ws_size,
                              hipStream_t stream)
{
    const float* X      = (const float*)d_in[0];
    const float* adj    = (const float*)d_in[1];
    const float* adjm   = (const float*)d_in[2];
    const float* Theta0 = (const float*)d_in[3];
    const float* bias0  = (const float*)d_in[4];
    const float* Wt0    = (const float*)d_in[5];
    const float* bt0    = (const float*)d_in[6];
    const float* Theta1 = (const float*)d_in[7];
    const float* bias1  = (const float*)d_in[8];
    const float* Wt1    = (const float*)d_in[9];
    const float* bt1    = (const float*)d_in[10];
    const float* Wout   = (const float*)d_in[11];
    const float* bout   = (const float*)d_in[12];
    (void)in_sizes; (void)n_in; (void)out_size; (void)ws_size;

    char* p = (char*)d_ws;
    int*    t_idx  = (int*)p;    p += (size_t)2 * NN * LISTCAP * sizeof(int);
    float*  t_val  = (float*)p;  p += (size_t)2 * NN * LISTCAP * sizeof(float);
    int*    t_cnt  = (int*)p;    p += (size_t)2 * NN * sizeof(int);
    float*  t_deg  = (float*)p;  p += (size_t)2 * NN * sizeof(float);
    float*  t_ideg = (float*)p;  p += (size_t)2 * NN * sizeof(float);
    float2* t_sc   = (float2*)p; p += (size_t)2 * NN * sizeof(float2);
    float*  I1     = (float*)p;  p += (size_t)NSITES * CC * sizeof(float);
    u16*    mHi    = (u16*)p;    p += (size_t)NSITES * 128 * sizeof(u16);
    u16*    mLo    = (u16*)p;    p += (size_t)NSITES * 128 * sizeof(u16);
    u16*    thHi   = (u16*)p;    p += (size_t)96 * 128 * sizeof(u16);
    u16*    thLo   = (u16*)p;    p += (size_t)96 * 128 * sizeof(u16);
    u16*    wtHi   = (u16*)p;    p += (size_t)1024 * sizeof(u16);
    u16*    wtLo   = (u16*)p;    p += (size_t)1024 * sizeof(u16);

    hipLaunchKernelGGL(topk_prep, dim3(2 * NN / 4), dim3(256), 0, stream,
                       adj, adjm, t_idx, t_val, t_cnt, t_deg, t_ideg, t_sc);
    hipLaunchKernelGGL(stower0_tcn0, dim3(NSITES / 256 + 13), dim3(256), 0, stream,
                       X, t_idx, t_val, t_cnt, t_deg, Theta0, bias0, Wt0, bt0,
                       Theta1, Wt1, thHi, thLo, wtHi, wtLo, I1);
    hipLaunchKernelGGL(stower1_agg, dim3(NSITES / 8), dim3(256), 0, stream,
                       I1, t_idx, t_val, t_cnt, t_ideg, mHi, mLo);
    hipLaunchKernelGGL(stower1_gemm, dim3(NSITES / 96), dim3(256), 0, stream,
                       mHi, mLo, thHi, thLo, wtHi, wtLo, t_sc,
                       bias1, bt1, Wout, bout, (float*)d_out);
}